// Round 14
// baseline (241.677 us; speedup 1.0000x reference)
//
#include <hip/hip_runtime.h>

// NSDE pricer, R16: pairwise spin-sync replaces block barriers (on R15 base).
// R15: 156.5 us, VALUBusy 74%, MfmaUtil 13.8%, occ 36% (grid-capped), VGPR 48.
// Busy model: ~1086 issue-cyc/mlp_one, ~512 = irreducible tanh trans chains.
// The 26% idle is barrier-structural: __syncthreads syncs all 8 waves but
// only the 2 waves of a role pair exchange data (4 tile-pairs independent),
// and the barrier RE-ALIGNS all waves into the same low-ILP post-barrier
// region each phase. Fix: per-pair handshake in LDS -- publish fx ->
// lgkmcnt(0) -> lane0 writes own counter (=2*step+phase, monotonic) -> spin
// on PARTNER counter (broadcast ds_read + s_sleep) -> read fx2. In-order
// per-wave DS pipe + explicit drain gives writer-side ordering; reader poll
// + memory clobber gives read-side. Slot reuse race-free without double
// buffering: a wave reaches its step-(n+1) overwrite only after observing
// partner >= 2n+2, which is after the partner consumed step-n data.
// Everything else identical to R15: layer1 via MFMA (sigma-permuted hidden,
// double-bf16 S/wS/wT), swapped-MFMA layer2, lane-local layer3 + 2-shfl,
// k=2/ln2 in weights, S/V register-carried, anti-LICM asm barrier,
// block 512 = 8 waves = 1 path, grid 512, waves_per_eu(4).

#define N_PATHS 512
#define N_STEPS 32
#define B_OPTS  64
#define HID     64

#define TANH_K 2.8853900817779268f   // 2/ln2: tanh(x) = 1 - 2/(2^(k*x)+1)

typedef __attribute__((ext_vector_type(8))) short bf16x8;   // 8 bf16 (4 VGPRs)
typedef __attribute__((ext_vector_type(4))) float f32x4;
typedef __attribute__((ext_vector_type(4))) unsigned u32x4;

__device__ __forceinline__ float tanh_from_scaled(float a) {
    // a = k*x already (k folded into weights). tanh = 1 - 2/(2^a + 1).
    float u = __builtin_amdgcn_exp2f(a);
    float r = __builtin_amdgcn_rcpf(u + 1.0f);
    return fmaf(-2.0f, r, 1.0f);
}

__device__ __forceinline__ short f2bf(float f) {            // fp32 -> bf16 RNE
    union { float f; unsigned u; } c; c.f = f;
    unsigned u = c.u + 0x7FFFu + ((c.u >> 16) & 1u);
    return (short)(u >> 16);
}

__device__ __forceinline__ unsigned cvt_pk_bf16(float lo, float hi) {
    // packs lo -> [15:0], hi -> [31:16] as bf16 (RNE), single VALU op.
    unsigned r;
    asm("v_cvt_pk_bf16_f32 %0, %1, %2" : "=v"(r) : "v"(lo), "v"(hi));
    return r;
}

__device__ __forceinline__ void bsplit(float x, float& hi, float& lo) {
    // double-bf16 split: x = hi + lo with hi = bf16(x) (as fp32), lo residual.
    const unsigned u = cvt_pk_bf16(x, x);
    hi = __builtin_bit_cast(float, u << 16);
    lo = x - hi;
}

// One net: layer1 via MFMA-1 (4 tiles) + tanh + pack; layer2 MFMA-2
// (A=k*W1 sigma-frags, B=h1, C=k*b1); layer3 lane-local tanh-dot + 2-shfl
// reduce. Returns f for row nh, valid at ALL lanes.
__device__ __forceinline__ float mlp_one(
    int net, int q,
    bf16x8 svt,                                 // input frag (q-masked by caller)
    const uint4*  __restrict__ w0ap,            // LDS W0 A-frags, lane-offset
    const float*  __restrict__ b0e,             // LDS, k*(b0+rf*w_rf), [4][64]
    const uint4*  __restrict__ w1p,             // LDS W1 frags (k*W1), lane-offset
    const float*  __restrict__ b1k,             // LDS, k*b1, [4][64]
    const float (&w2v)[4][4], float b2s)        // [nt][r] = W2[net*64+16nt+4q+r]
{
    // Block LICM: nothing memory-derived carried across phases/steps
    // (R5/R7 lesson: hoisted LDS values spill to scratch -> 1.7 GB HBM).
    asm volatile("" ::: "memory");
    // ---- frag loads early: DS latency hides under MFMA/trans ----
    uint4 wfr[8];
#pragma unroll
    for (int i = 0; i < 8; ++i) wfr[i] = w1p[(net * 8 + i) * 64];
    uint4 w0f[4];
#pragma unroll
    for (int mt = 0; mt < 4; ++mt) w0f[mt] = w0ap[(net * 4 + mt) * 64];

    // ---- layer1 (MFMA pipe): preact[H=16mt+4q+r][row=nh] ----
    f32x4 c1[4];
#pragma unroll
    for (int mt = 0; mt < 4; ++mt) {
        f32x4 ci = *(const f32x4*)&b0e[net * 64 + mt * 16 + 4 * q];
        c1[mt] = __builtin_amdgcn_mfma_f32_16x16x32_bf16(
                     __builtin_bit_cast(bf16x8, w0f[mt]), svt, ci, 0, 0, 0);
    }
    // ---- tanh + pack directly into MFMA-2 B-frag order (sigma trick) ----
    u32x4 afr[2];
#pragma unroll
    for (int x = 0; x < 2; ++x) {
        afr[x][0] = cvt_pk_bf16(tanh_from_scaled(c1[2 * x][0]),
                                tanh_from_scaled(c1[2 * x][1]));
        afr[x][1] = cvt_pk_bf16(tanh_from_scaled(c1[2 * x][2]),
                                tanh_from_scaled(c1[2 * x][3]));
        afr[x][2] = cvt_pk_bf16(tanh_from_scaled(c1[2 * x + 1][0]),
                                tanh_from_scaled(c1[2 * x + 1][1]));
        afr[x][3] = cvt_pk_bf16(tanh_from_scaled(c1[2 * x + 1][2]),
                                tanh_from_scaled(c1[2 * x + 1][3]));
    }
    const bf16x8 h0 = __builtin_bit_cast(bf16x8, afr[0]);
    const bf16x8 h1 = __builtin_bit_cast(bf16x8, afr[1]);

    // ---- layer2+3: C[m=4q+r][n=nh] = h2[row=nh][hid2=16nt+4q+r] ----
    float s = 0.0f;
#pragma unroll
    for (int nt = 0; nt < 4; ++nt) {
        f32x4 c = *(const f32x4*)&b1k[net * 64 + nt * 16 + 4 * q];  // b128 bcast
        c = __builtin_amdgcn_mfma_f32_16x16x32_bf16(
                __builtin_bit_cast(bf16x8, wfr[nt * 2 + 0]), h0, c, 0, 0, 0);
        c = __builtin_amdgcn_mfma_f32_16x16x32_bf16(
                __builtin_bit_cast(bf16x8, wfr[nt * 2 + 1]), h1, c, 0, 0, 0);
#pragma unroll
        for (int r = 0; r < 4; ++r)
            s = fmaf(tanh_from_scaled(c[r]), w2v[nt][r], s);
    }
    s += __shfl_xor(s, 16);                      // reduce over q-groups
    s += __shfl_xor(s, 32);
    return s + b2s;
}

__global__ __launch_bounds__(512)
__attribute__((amdgpu_waves_per_eu(4)))
void nsde_kernel(
    const float* __restrict__ S0p, const float* __restrict__ Kp,
    const float* __restrict__ Tp,  const float* __restrict__ rfp,
    const float* __restrict__ Z1,  const float* __restrict__ Z2,
    const float* __restrict__ W0,  const float* __restrict__ b0,
    const float* __restrict__ W1,  const float* __restrict__ b1,
    const float* __restrict__ W2,  const float* __restrict__ b2,
    float* __restrict__ out, float* __restrict__ ws, int use_ws)
{
    const int tid  = threadIdx.x;
    const int wave = tid >> 6;                      // 0..7
    const int lane = tid & 63;
    const int q    = lane >> 4;
    const int nh   = lane & 15;
    const int t    = wave >> 1;                     // tile 0..3
    const int role = wave & 1;                      // 0: nets 0/2, 1: nets 1/3
    const int path = blockIdx.x;                    // one path per block
    const int row  = t * 16 + nh;                   // this lane's option row

    __shared__ uint4  w0a[1024];                    // W0 A-frags, 16 KB
    __shared__ uint4  w1f[2048];                    // k*W1 bf16 frags, 32 KB
    __shared__ __align__(16) float b0e[4 * 64];     // k*(b0 + rf*w_rf), f32
    __shared__ __align__(16) float b1k[4 * 64];     // k*b1, f32
    __shared__ float2 fx2[64];                      // phase-1 exchange [row]
    __shared__ float2 gx2[64];                      // phase-2 exchange
    __shared__ unsigned cnt[8];                     // per-wave phase counters

    const float rf = rfp[0];

    // ---- one-time staging: b0e, b1k, counters ----
    if (tid < 256) {
        const int net = tid >> 6, kk = tid & 63;
        b0e[tid] = TANH_K * fmaf(rf, W0[net * 256 + 128 + kk], b0[tid]);
        b1k[tid] = TANH_K * b1[tid];
    }
    if (tid < 8) cnt[tid] = 0u;

    // ---- one-time staging: W0 A-frags (double-bf16 wS, wT; single wV) ----
    // frag (net,mt) lane(q0,nh0): q0==0 slots: wShi,wShi | wSlo,wV | wThi,wThi
    // | wTlo,0 for hidden H = 16mt + nh0; all other lanes zero.
#pragma unroll
    for (int it = 0; it < 2; ++it) {
        const int f   = it * 512 + tid;             // 0..1023
        const int ls  = f & 63;
        const int mt  = (f >> 6) & 3;
        const int nts = f >> 8;                     // net
        uint4 fr = {0u, 0u, 0u, 0u};
        if ((ls >> 4) == 0) {
            const int H = mt * 16 + (ls & 15);
            const float wS = TANH_K * W0[nts * 256 + 0   + H];
            const float wV = TANH_K * W0[nts * 256 + 64  + H];
            const float wT = TANH_K * W0[nts * 256 + 192 + H];
            const unsigned sh = (unsigned)(unsigned short)f2bf(wS);
            const float shf   = __builtin_bit_cast(float, sh << 16);
            const unsigned th = (unsigned)(unsigned short)f2bf(wT);
            const float thf   = __builtin_bit_cast(float, th << 16);
            fr.x = sh | (sh << 16);
            fr.y = (unsigned)(unsigned short)f2bf(wS - shf)
                 | ((unsigned)(unsigned short)f2bf(wV) << 16);
            fr.z = th | (th << 16);
            fr.w = (unsigned)(unsigned short)f2bf(wT - thf);
        }
        w0a[f] = fr;
    }

    // ---- one-time staging: k*W1 -> LDS bf16 frags, sigma k-ordering ----
    // frag f: nh=f&15, q=(f>>4)&3, kh=(f>>6)&1, nt=(f>>7)&3, net=(f>>9)&3
    // element j holds k*W1[H = 16*(2kh + (j>>2)) + 4q + (j&3)][16nt + nh].
#pragma unroll
    for (int it = 0; it < 4; ++it) {
        const int f   = it * 512 + tid;
        const int fnh = f & 15;
        const int fq  = (f >> 4) & 3;
        const int fkh = (f >> 6) & 1;
        const int fnt = (f >> 7) & 3;
        const int fnet= (f >> 9) & 3;
        bf16x8 fr;
#pragma unroll
        for (int j = 0; j < 8; ++j) {
            const int H = 16 * (2 * fkh + (j >> 2)) + 4 * fq + (j & 3);
            fr[j] = f2bf(TANH_K * W1[fnet * 4096 + H * 64 + fnt * 16 + fnh]);
        }
        w1f[f] = __builtin_bit_cast(uint4, fr);
    }

    // ---- per-lane constants (only this wave's two nets) ----
    const float dta  = Tp[row] * (1.0f / N_STEPS);
    const float sqdt = sqrtf(dta);
    const int netA = role;                          // phase-1 net
    const int netB = role + 2;                      // phase-2 net

    float w2vA[4][4], w2vB[4][4];                   // [nt][r] at hid=16nt+4q+r
#pragma unroll
    for (int nt = 0; nt < 4; ++nt)
#pragma unroll
        for (int r = 0; r < 4; ++r) {
            const int hid = nt * 16 + 4 * q + r;
            w2vA[nt][r] = W2[netA * 64 + hid];
            w2vB[nt][r] = W2[netB * 64 + hid];
        }
    const float b2A = b2[netA], b2B = b2[netB];

    float Sreg = S0p[row];                          // register-carried state
    float Vreg = 0.2f;

    __syncthreads();                                // staging visible to all

    const uint4* __restrict__ w0ap = &w0a[lane];    // lane-contiguous bases
    const uint4* __restrict__ w1p  = &w1f[lane];
    const float* __restrict__ z1p  = Z1 + path * N_STEPS;
    const float* __restrict__ z2p  = Z2 + path * N_STEPS;
    const bool q0 = (q == 0);
    volatile unsigned* cown = &cnt[wave];           // my phase counter
    volatile unsigned* cpar = &cnt[wave ^ 1];       // partner (other role)

    for (int step = 0; step < N_STEPS; ++step) {
        const float z1 = z1p[step];
        const float z2 = z2p[step];
        const float tA = dta * (float)step;

        // per-step input-frag parts (shared by both phases)
        float th, tl; bsplit(tA, th, tl);
        const unsigned td2 = cvt_pk_bf16(th, tl);
        const unsigned td3 = cvt_pk_bf16(th, 0.0f);

        // ---- phase 1: my net (role) on (S, V, rf, t) ----
        {
            float sh, sl; bsplit(Sreg, sh, sl);
            u32x4 sv;
            sv[0] = q0 ? cvt_pk_bf16(sh, sl)   : 0u;
            sv[1] = q0 ? cvt_pk_bf16(sh, Vreg) : 0u;
            sv[2] = q0 ? td2 : 0u;
            sv[3] = q0 ? td3 : 0u;
            const float f = mlp_one(netA, q, __builtin_bit_cast(bf16x8, sv),
                                    w0ap, b0e, w1p, b1k, w2vA, b2A);
            if (q0) { if (role == 0) fx2[row].x = f; else fx2[row].y = f; }
        }
        // publish: drain data write, then bump own counter; poll partner.
        {
            const unsigned tgt = (unsigned)(2 * step + 1);
            asm volatile("s_waitcnt lgkmcnt(0)" ::: "memory");
            if (lane == 0) *cown = tgt;
            while (*cpar < tgt) __builtin_amdgcn_s_sleep(1);
            asm volatile("" ::: "memory");
        }
        {   // both waves update S redundantly (deterministic, same inputs)
            const float2 fp = fx2[row];
            Sreg = Sreg * fmaf(fp.y, z1, fmaf(fp.x, dta, 1.0f));
        }

        // ---- phase 2: my net (role+2) on (S_new, V, rf, t) ----
        {
            float sh, sl; bsplit(Sreg, sh, sl);
            u32x4 sv;
            sv[0] = q0 ? cvt_pk_bf16(sh, sl)   : 0u;
            sv[1] = q0 ? cvt_pk_bf16(sh, Vreg) : 0u;
            sv[2] = q0 ? td2 : 0u;
            sv[3] = q0 ? td3 : 0u;
            const float g = mlp_one(netB, q, __builtin_bit_cast(bf16x8, sv),
                                    w0ap, b0e, w1p, b1k, w2vB, b2B);
            if (q0) { if (role == 0) gx2[row].x = g; else gx2[row].y = g; }
        }
        {
            const unsigned tgt = (unsigned)(2 * step + 2);
            asm volatile("s_waitcnt lgkmcnt(0)" ::: "memory");
            if (lane == 0) *cown = tgt;
            while (*cpar < tgt) __builtin_amdgcn_s_sleep(1);
            asm volatile("" ::: "memory");
        }
        {
            const float2 gp = gx2[row];
            Vreg = Vreg * fmaf(gp.y, sqdt * z2, fmaf(gp.x, dta, 1.0f));
        }
    }

    // ---- payoff: one lane per row writes (Sreg in registers, no sync) ----
    if (role == 0 && q == 0) {
        const float Tt   = dta * (float)N_STEPS;
        const float disc = __builtin_amdgcn_exp2f(-rf * Tt * 1.4426950408889634f)
                           * (1.0f / (float)N_PATHS);
        const float Kv = Kp[row];
        const float p1 = (Sreg - Kv < 0.0f) ? 0.0f : Sreg;
        const float v  = disc * p1;
        if (use_ws) ws[path * 64 + row] = v;
        else        atomicAdd(&out[row], v);
    }
}

__global__ void reduce_kernel(const float* __restrict__ ws, float* __restrict__ out) {
    __shared__ float acc[4][64];
    const int o = threadIdx.x & 63, g = threadIdx.x >> 6;
    float s = 0.0f;
    for (int b = g; b < N_PATHS; b += 4) s += ws[b * 64 + o];
    acc[g][o] = s;
    __syncthreads();
    if (threadIdx.x < 64)
        out[threadIdx.x] = acc[0][threadIdx.x] + acc[1][threadIdx.x]
                         + acc[2][threadIdx.x] + acc[3][threadIdx.x];
}

__global__ void zero_out_kernel(float* __restrict__ out) {
    out[threadIdx.x] = 0.0f;
}

extern "C" void kernel_launch(void* const* d_in, const int* in_sizes, int n_in,
                              void* d_out, int out_size, void* d_ws, size_t ws_size,
                              hipStream_t stream) {
    const float* S0p = (const float*)d_in[0];
    const float* Kp  = (const float*)d_in[1];
    const float* Tp  = (const float*)d_in[2];
    const float* rfp = (const float*)d_in[3];
    const float* Z1  = (const float*)d_in[4];
    const float* Z2  = (const float*)d_in[5];
    const float* W0  = (const float*)d_in[6];
    const float* b0  = (const float*)d_in[7];
    const float* W1  = (const float*)d_in[8];
    const float* b1  = (const float*)d_in[9];
    const float* W2  = (const float*)d_in[10];
    const float* b2  = (const float*)d_in[11];
    float* out = (float*)d_out;
    float* wsf = (float*)d_ws;

    const int use_ws = (ws_size >= (size_t)(N_PATHS * 64 * sizeof(float))) ? 1 : 0;

    if (!use_ws) zero_out_kernel<<<1, B_OPTS, 0, stream>>>(out);
    nsde_kernel<<<N_PATHS, 512, 0, stream>>>(S0p, Kp, Tp, rfp, Z1, Z2,
                                             W0, b0, W1, b1, W2, b2, out, wsf, use_ws);
    if (use_ws) reduce_kernel<<<1, 256, 0, stream>>>(wsf, out);
}

// Round 15
// 235.505 us; speedup vs baseline: 1.0262x; 1.0262x over previous
//
#include <hip/hip_runtime.h>

// NSDE pricer, R17: R15 barriers restored + layer3 r-fold + dead-mask removal.
// R16 post-mortem: pairwise spin-sync NEUTRAL (156.2 vs 156.5 us) -> the 26%
// idle is dependent-chain latency, not barrier alignment; block barriers
// restored (simpler). Issue accounting: busy 117 us = 55 us trans floor +
// ~62 us surrounding arithmetic. Two safe cuts:
//  1. Layer3-only r-fold (the provably-NaN-free half of R12's fold):
//     s = sum(w2*tanh(c)) = w2sum - 2*sum(w2*r), r = rcp(exp2(c)+1) in [0,1],
//     exact saturation (rcp(inf)=0). Lane-local scalar algebra only — no
//     MFMA/LDS staging change (R13's NaN suspects were L1-side: -2k*W1 frags
//     + rowsum C-init; NOT retried). Saves 16 fma/mlp_one.
//  2. Input B-frag q0-masking removed: W0 A-frags are zero for lanes q!=0,
//     so those k-slots contribute 0 regardless of B (8 cndmask/step dead).
// Everything else identical to R15 (156.5 us, passed): layer1 via MFMA
// (sigma-permuted hidden, double-bf16 S/wS/wT), swapped-MFMA layer2,
// lane-local layer3 + 2-shfl reduce, k=2/ln2 in weights, S/V register-
// carried, 2 block barriers/step, anti-LICM asm barrier, block 512 = 8
// waves = 1 path, grid 512, waves_per_eu(4).

#define N_PATHS 512
#define N_STEPS 32
#define B_OPTS  64
#define HID     64

#define TANH_K 2.8853900817779268f   // 2/ln2: tanh(x) = 1 - 2/(2^(k*x)+1)

typedef __attribute__((ext_vector_type(8))) short bf16x8;   // 8 bf16 (4 VGPRs)
typedef __attribute__((ext_vector_type(4))) float f32x4;
typedef __attribute__((ext_vector_type(4))) unsigned u32x4;

__device__ __forceinline__ float tanh_from_scaled(float a) {
    // a = k*x already (k folded into weights). tanh = 1 - 2/(2^a + 1).
    float u = __builtin_amdgcn_exp2f(a);
    float r = __builtin_amdgcn_rcpf(u + 1.0f);
    return fmaf(-2.0f, r, 1.0f);
}

__device__ __forceinline__ float sig2r(float a) {
    // r = 1/(2^a + 1) in [0,1]; tanh(x) = 1 - 2r. rcp(inf)=0: exact sat.
    float u = __builtin_amdgcn_exp2f(a);
    return __builtin_amdgcn_rcpf(u + 1.0f);
}

__device__ __forceinline__ short f2bf(float f) {            // fp32 -> bf16 RNE
    union { float f; unsigned u; } c; c.f = f;
    unsigned u = c.u + 0x7FFFu + ((c.u >> 16) & 1u);
    return (short)(u >> 16);
}

__device__ __forceinline__ unsigned cvt_pk_bf16(float lo, float hi) {
    // packs lo -> [15:0], hi -> [31:16] as bf16 (RNE), single VALU op.
    unsigned r;
    asm("v_cvt_pk_bf16_f32 %0, %1, %2" : "=v"(r) : "v"(lo), "v"(hi));
    return r;
}

__device__ __forceinline__ void bsplit(float x, float& hi, float& lo) {
    // double-bf16 split: x = hi + lo with hi = bf16(x) (as fp32), lo residual.
    const unsigned u = cvt_pk_bf16(x, x);
    hi = __builtin_bit_cast(float, u << 16);
    lo = x - hi;
}

// One net: layer1 via MFMA-1 (4 tiles) + tanh + pack; layer2 MFMA-2
// (A=k*W1 sigma-frags, B=h1, C=k*b1); layer3 lane-local r-dot
// (s = w2sum + sum((-2w2)*r)) + 2-shfl reduce. Returns f for row nh,
// valid at ALL lanes.
__device__ __forceinline__ float mlp_one(
    int net, int q,
    bf16x8 svt,                                 // input frag (A-side zeros mask)
    const uint4*  __restrict__ w0ap,            // LDS W0 A-frags, lane-offset
    const float*  __restrict__ b0e,             // LDS, k*(b0+rf*w_rf), [4][64]
    const uint4*  __restrict__ w1p,             // LDS W1 frags (k*W1), lane-offset
    const float*  __restrict__ b1k,             // LDS, k*b1, [4][64]
    const float (&w2n)[4][4], float w2sum, float b2s)
{
    // Block LICM: nothing memory-derived carried across phases/steps
    // (R5/R7 lesson: hoisted LDS values spill to scratch -> 1.7 GB HBM).
    asm volatile("" ::: "memory");
    // ---- frag loads early: DS latency hides under MFMA/trans ----
    uint4 wfr[8];
#pragma unroll
    for (int i = 0; i < 8; ++i) wfr[i] = w1p[(net * 8 + i) * 64];
    uint4 w0f[4];
#pragma unroll
    for (int mt = 0; mt < 4; ++mt) w0f[mt] = w0ap[(net * 4 + mt) * 64];

    // ---- layer1 (MFMA pipe): preact[H=16mt+4q+r][row=nh] ----
    f32x4 c1[4];
#pragma unroll
    for (int mt = 0; mt < 4; ++mt) {
        f32x4 ci = *(const f32x4*)&b0e[net * 64 + mt * 16 + 4 * q];
        c1[mt] = __builtin_amdgcn_mfma_f32_16x16x32_bf16(
                     __builtin_bit_cast(bf16x8, w0f[mt]), svt, ci, 0, 0, 0);
    }
    // ---- tanh + pack directly into MFMA-2 B-frag order (sigma trick) ----
    u32x4 afr[2];
#pragma unroll
    for (int x = 0; x < 2; ++x) {
        afr[x][0] = cvt_pk_bf16(tanh_from_scaled(c1[2 * x][0]),
                                tanh_from_scaled(c1[2 * x][1]));
        afr[x][1] = cvt_pk_bf16(tanh_from_scaled(c1[2 * x][2]),
                                tanh_from_scaled(c1[2 * x][3]));
        afr[x][2] = cvt_pk_bf16(tanh_from_scaled(c1[2 * x + 1][0]),
                                tanh_from_scaled(c1[2 * x + 1][1]));
        afr[x][3] = cvt_pk_bf16(tanh_from_scaled(c1[2 * x + 1][2]),
                                tanh_from_scaled(c1[2 * x + 1][3]));
    }
    const bf16x8 h0 = __builtin_bit_cast(bf16x8, afr[0]);
    const bf16x8 h1 = __builtin_bit_cast(bf16x8, afr[1]);

    // ---- layer2+3: C[m=4q+r][n=nh]; s = w2sum + sum((-2w2)*r) ----
    float s = w2sum;
#pragma unroll
    for (int nt = 0; nt < 4; ++nt) {
        f32x4 c = *(const f32x4*)&b1k[net * 64 + nt * 16 + 4 * q];  // b128 bcast
        c = __builtin_amdgcn_mfma_f32_16x16x32_bf16(
                __builtin_bit_cast(bf16x8, wfr[nt * 2 + 0]), h0, c, 0, 0, 0);
        c = __builtin_amdgcn_mfma_f32_16x16x32_bf16(
                __builtin_bit_cast(bf16x8, wfr[nt * 2 + 1]), h1, c, 0, 0, 0);
#pragma unroll
        for (int r = 0; r < 4; ++r)
            s = fmaf(w2n[nt][r], sig2r(c[r]), s);
    }
    s += __shfl_xor(s, 16);                      // reduce over q-groups
    s += __shfl_xor(s, 32);
    return s + b2s;
}

__global__ __launch_bounds__(512)
__attribute__((amdgpu_waves_per_eu(4)))
void nsde_kernel(
    const float* __restrict__ S0p, const float* __restrict__ Kp,
    const float* __restrict__ Tp,  const float* __restrict__ rfp,
    const float* __restrict__ Z1,  const float* __restrict__ Z2,
    const float* __restrict__ W0,  const float* __restrict__ b0,
    const float* __restrict__ W1,  const float* __restrict__ b1,
    const float* __restrict__ W2,  const float* __restrict__ b2,
    float* __restrict__ out, float* __restrict__ ws, int use_ws)
{
    const int tid  = threadIdx.x;
    const int wave = tid >> 6;                      // 0..7
    const int lane = tid & 63;
    const int q    = lane >> 4;
    const int nh   = lane & 15;
    const int t    = wave >> 1;                     // tile 0..3
    const int role = wave & 1;                      // 0: nets 0/2, 1: nets 1/3
    const int path = blockIdx.x;                    // one path per block
    const int row  = t * 16 + nh;                   // this lane's option row

    __shared__ uint4  w0a[1024];                    // W0 A-frags, 16 KB
    __shared__ uint4  w1f[2048];                    // k*W1 bf16 frags, 32 KB
    __shared__ __align__(16) float b0e[4 * 64];     // k*(b0 + rf*w_rf), f32
    __shared__ __align__(16) float b1k[4 * 64];     // k*b1, f32
    __shared__ float2 fx2[64];                      // phase-1 exchange [row]
    __shared__ float2 gx2[64];                      // phase-2 exchange

    const float rf = rfp[0];

    // ---- one-time staging: b0e, b1k ----
    if (tid < 256) {
        const int net = tid >> 6, kk = tid & 63;
        b0e[tid] = TANH_K * fmaf(rf, W0[net * 256 + 128 + kk], b0[tid]);
        b1k[tid] = TANH_K * b1[tid];
    }

    // ---- one-time staging: W0 A-frags (double-bf16 wS, wT; single wV) ----
    // frag (net,mt) lane(q0,nh0): q0==0 slots: wShi,wShi | wSlo,wV | wThi,wThi
    // | wTlo,0 for hidden H = 16mt + nh0; all other lanes zero (this zeroing
    // is the k-slot mask -- B side needs no masking).
#pragma unroll
    for (int it = 0; it < 2; ++it) {
        const int f   = it * 512 + tid;             // 0..1023
        const int ls  = f & 63;
        const int mt  = (f >> 6) & 3;
        const int nts = f >> 8;                     // net
        uint4 fr = {0u, 0u, 0u, 0u};
        if ((ls >> 4) == 0) {
            const int H = mt * 16 + (ls & 15);
            const float wS = TANH_K * W0[nts * 256 + 0   + H];
            const float wV = TANH_K * W0[nts * 256 + 64  + H];
            const float wT = TANH_K * W0[nts * 256 + 192 + H];
            const unsigned sh = (unsigned)(unsigned short)f2bf(wS);
            const float shf   = __builtin_bit_cast(float, sh << 16);
            const unsigned th = (unsigned)(unsigned short)f2bf(wT);
            const float thf   = __builtin_bit_cast(float, th << 16);
            fr.x = sh | (sh << 16);
            fr.y = (unsigned)(unsigned short)f2bf(wS - shf)
                 | ((unsigned)(unsigned short)f2bf(wV) << 16);
            fr.z = th | (th << 16);
            fr.w = (unsigned)(unsigned short)f2bf(wT - thf);
        }
        w0a[f] = fr;
    }

    // ---- one-time staging: k*W1 -> LDS bf16 frags, sigma k-ordering ----
    // frag f: nh=f&15, q=(f>>4)&3, kh=(f>>6)&1, nt=(f>>7)&3, net=(f>>9)&3
    // element j holds k*W1[H = 16*(2kh + (j>>2)) + 4q + (j&3)][16nt + nh].
#pragma unroll
    for (int it = 0; it < 4; ++it) {
        const int f   = it * 512 + tid;
        const int fnh = f & 15;
        const int fq  = (f >> 4) & 3;
        const int fkh = (f >> 6) & 1;
        const int fnt = (f >> 7) & 3;
        const int fnet= (f >> 9) & 3;
        bf16x8 fr;
#pragma unroll
        for (int j = 0; j < 8; ++j) {
            const int H = 16 * (2 * fkh + (j >> 2)) + 4 * fq + (j & 3);
            fr[j] = f2bf(TANH_K * W1[fnet * 4096 + H * 64 + fnt * 16 + fnh]);
        }
        w1f[f] = __builtin_bit_cast(uint4, fr);
    }

    // ---- per-lane constants (only this wave's two nets) ----
    const float dta  = Tp[row] * (1.0f / N_STEPS);
    const float sqdt = sqrtf(dta);
    const int netA = role;                          // phase-1 net
    const int netB = role + 2;                      // phase-2 net

    float w2nA[4][4], w2nB[4][4];                   // -2*W2 at hid=16nt+4q+r
    float w2sA = 0.0f, w2sB = 0.0f;                 // per-lane partial sum(W2)
#pragma unroll
    for (int nt = 0; nt < 4; ++nt)
#pragma unroll
        for (int r = 0; r < 4; ++r) {
            const int hid = nt * 16 + 4 * q + r;
            const float a2  = W2[netA * 64 + hid];
            const float b2v = W2[netB * 64 + hid];
            w2nA[nt][r] = -2.0f * a2;  w2sA += a2;
            w2nB[nt][r] = -2.0f * b2v; w2sB += b2v;
        }
    const float b2A = b2[netA], b2B = b2[netB];

    float Sreg = S0p[row];                          // register-carried state
    float Vreg = 0.2f;

    __syncthreads();

    const uint4* __restrict__ w0ap = &w0a[lane];    // lane-contiguous bases
    const uint4* __restrict__ w1p  = &w1f[lane];
    const float* __restrict__ z1p  = Z1 + path * N_STEPS;
    const float* __restrict__ z2p  = Z2 + path * N_STEPS;
    const bool q0 = (q == 0);

    for (int step = 0; step < N_STEPS; ++step) {
        const float z1 = z1p[step];
        const float z2 = z2p[step];
        const float tA = dta * (float)step;

        // per-step input-frag parts (shared by both phases; no q-masking --
        // W0 A-frag zeros on lanes q!=0 already mask those k-slots)
        float th, tl; bsplit(tA, th, tl);
        const unsigned td2 = cvt_pk_bf16(th, tl);
        const unsigned td3 = cvt_pk_bf16(th, 0.0f);

        // ---- phase 1: my net (role) on (S, V, rf, t) ----
        {
            float sh, sl; bsplit(Sreg, sh, sl);
            u32x4 sv;
            sv[0] = cvt_pk_bf16(sh, sl);
            sv[1] = cvt_pk_bf16(sh, Vreg);
            sv[2] = td2;
            sv[3] = td3;
            const float f = mlp_one(netA, q, __builtin_bit_cast(bf16x8, sv),
                                    w0ap, b0e, w1p, b1k, w2nA, w2sA, b2A);
            if (q0) { if (role == 0) fx2[row].x = f; else fx2[row].y = f; }
        }
        __syncthreads();
        {   // both waves update S redundantly (deterministic, same inputs)
            const float2 fp = fx2[row];
            Sreg = Sreg * fmaf(fp.y, z1, fmaf(fp.x, dta, 1.0f));
        }

        // ---- phase 2: my net (role+2) on (S_new, V, rf, t) ----
        {
            float sh, sl; bsplit(Sreg, sh, sl);
            u32x4 sv;
            sv[0] = cvt_pk_bf16(sh, sl);
            sv[1] = cvt_pk_bf16(sh, Vreg);
            sv[2] = td2;
            sv[3] = td3;
            const float g = mlp_one(netB, q, __builtin_bit_cast(bf16x8, sv),
                                    w0ap, b0e, w1p, b1k, w2nB, w2sB, b2B);
            if (q0) { if (role == 0) gx2[row].x = g; else gx2[row].y = g; }
        }
        __syncthreads();
        {
            const float2 gp = gx2[row];
            Vreg = Vreg * fmaf(gp.y, sqdt * z2, fmaf(gp.x, dta, 1.0f));
        }
    }

    // ---- payoff: one lane per row writes (Sreg in registers, no sync) ----
    if (role == 0 && q == 0) {
        const float Tt   = dta * (float)N_STEPS;
        const float disc = __builtin_amdgcn_exp2f(-rf * Tt * 1.4426950408889634f)
                           * (1.0f / (float)N_PATHS);
        const float Kv = Kp[row];
        const float p1 = (Sreg - Kv < 0.0f) ? 0.0f : Sreg;
        const float v  = disc * p1;
        if (use_ws) ws[path * 64 + row] = v;
        else        atomicAdd(&out[row], v);
    }
}

__global__ void reduce_kernel(const float* __restrict__ ws, float* __restrict__ out) {
    __shared__ float acc[4][64];
    const int o = threadIdx.x & 63, g = threadIdx.x >> 6;
    float s = 0.0f;
    for (int b = g; b < N_PATHS; b += 4) s += ws[b * 64 + o];
    acc[g][o] = s;
    __syncthreads();
    if (threadIdx.x < 64)
        out[threadIdx.x] = acc[0][threadIdx.x] + acc[1][threadIdx.x]
                         + acc[2][threadIdx.x] + acc[3][threadIdx.x];
}

__global__ void zero_out_kernel(float* __restrict__ out) {
    out[threadIdx.x] = 0.0f;
}

extern "C" void kernel_launch(void* const* d_in, const int* in_sizes, int n_in,
                              void* d_out, int out_size, void* d_ws, size_t ws_size,
                              hipStream_t stream) {
    const float* S0p = (const float*)d_in[0];
    const float* Kp  = (const float*)d_in[1];
    const float* Tp  = (const float*)d_in[2];
    const float* rfp = (const float*)d_in[3];
    const float* Z1  = (const float*)d_in[4];
    const float* Z2  = (const float*)d_in[5];
    const float* W0  = (const float*)d_in[6];
    const float* b0  = (const float*)d_in[7];
    const float* W1  = (const float*)d_in[8];
    const float* b1  = (const float*)d_in[9];
    const float* W2  = (const float*)d_in[10];
    const float* b2  = (const float*)d_in[11];
    float* out = (float*)d_out;
    float* wsf = (float*)d_ws;

    const int use_ws = (ws_size >= (size_t)(N_PATHS * 64 * sizeof(float))) ? 1 : 0;

    if (!use_ws) zero_out_kernel<<<1, B_OPTS, 0, stream>>>(out);
    nsde_kernel<<<N_PATHS, 512, 0, stream>>>(S0p, Kp, Tp, rfp, Z1, Z2,
                                             W0, b0, W1, b1, W2, b2, out, wsf, use_ws);
    if (use_ws) reduce_kernel<<<1, 256, 0, stream>>>(wsf, out);
}